// Round 1
// baseline (588.201 us; speedup 1.0000x reference)
//
#include <hip/hip_runtime.h>
#include <stdint.h>

typedef __bf16 bf16x8 __attribute__((ext_vector_type(8)));
typedef float f32x4 __attribute__((ext_vector_type(4)));

__device__ __forceinline__ float bf2f(unsigned short s) {
    union { unsigned u; float f; } x; x.u = ((unsigned)s) << 16; return x.f;
}
__device__ __forceinline__ unsigned short f2bf(float f) {
    union { float f; unsigned u; } x; x.f = f;
    unsigned r = x.u + 0x7fffu + ((x.u >> 16) & 1u);
    return (unsigned short)(r >> 16);
}

// ---------- CSR build ----------
__global__ void k_degree(const int* __restrict__ dst, int E, int* __restrict__ deg) {
    int i = blockIdx.x * blockDim.x + threadIdx.x;
    if (i < E) atomicAdd(&deg[dst[i]], 1);
}

__global__ void k_dinv(const int* __restrict__ deg, float* __restrict__ dinv, int N) {
    int i = blockIdx.x * blockDim.x + threadIdx.x;
    if (i < N) dinv[i] = rsqrtf((float)deg[i] + 1.0f);  // +1 = self loop
}

__global__ void k_scan(const int* __restrict__ deg, int* __restrict__ row_ptr, int N) {
    __shared__ int sums[1024];
    int t = threadIdx.x;
    int chunk = (N + 1023) >> 10;
    int lo = t * chunk;
    int hi = min(lo + chunk, N);
    int s = 0;
    for (int i = lo; i < hi; ++i) s += deg[i];
    sums[t] = s;
    __syncthreads();
    for (int off = 1; off < 1024; off <<= 1) {
        int v = sums[t];
        int u = (t >= off) ? sums[t - off] : 0;
        __syncthreads();
        sums[t] = v + u;
        __syncthreads();
    }
    int pre = (t == 0) ? 0 : sums[t - 1];
    for (int i = lo; i < hi; ++i) { row_ptr[i] = pre; pre += deg[i]; }
    if (t == 1023) row_ptr[N] = pre;
}

__global__ void k_scatter(const int* __restrict__ src, const int* __restrict__ dst, int E,
                          const float* __restrict__ dinv, const int* __restrict__ row_ptr,
                          int* __restrict__ fill, int* __restrict__ ssrc,
                          float* __restrict__ snorm) {
    int e = blockIdx.x * blockDim.x + threadIdx.x;
    if (e >= E) return;
    int s = src[e], d = dst[e];
    int pos = row_ptr[d] + atomicAdd(&fill[d], 1);
    ssrc[pos] = s;
    snorm[pos] = dinv[s] * dinv[d];
}

// ---------- conversions ----------
__global__ void k_cvt_x(const float4* __restrict__ x, ushort4* __restrict__ out, int n4) {
    int i = blockIdx.x * blockDim.x + threadIdx.x;
    if (i < n4) {
        float4 v = x[i];
        ushort4 o;
        o.x = f2bf(v.x); o.y = f2bf(v.y); o.z = f2bf(v.z); o.w = f2bf(v.w);
        out[i] = o;
    }
}

// W [K=128][realCols] f32 row-major -> fragment layout bf16:
// Wf[((kk*NT + n)*64 + lane)*8 + j] = W[kk*32 + (lane>>4)*8 + j][n*16 + (lane&15)]
__global__ void k_wfrag(const float* __restrict__ W, unsigned short* __restrict__ Wf,
                        int Ncol, int realCols) {
    int NT = Ncol >> 4;
    int total = 4 * NT * 64 * 8;
    int idx = blockIdx.x * blockDim.x + threadIdx.x;
    if (idx >= total) return;
    int j = idx & 7;
    int l = (idx >> 3) & 63;
    int t = idx >> 9;          // kk*NT + n
    int n = t % NT;
    int kk = t / NT;
    int k = kk * 32 + ((l >> 4) << 3) + j;
    int c = (n << 4) + (l & 15);
    float v = (c < realCols) ? W[k * realCols + c] : 0.0f;
    Wf[idx] = f2bf(v);
}

// ---------- GEMM: H[Npad][NT*16] = A[Npad][128] @ W (frag layout) ----------
template<int NT>
__global__ __launch_bounds__(256) void k_gemm(const unsigned short* __restrict__ A,
                                              const unsigned short* __restrict__ Wf,
                                              unsigned short* __restrict__ Hout) {
    int lane = threadIdx.x & 63;
    int wv = threadIdx.x >> 6;
    int rb = blockIdx.x * 4 + wv;
    size_t row0 = (size_t)rb * 16;
    const unsigned short* arow = A + (row0 + (lane & 15)) * 128 + ((lane >> 4) << 3);
    f32x4 acc[NT];
#pragma unroll
    for (int n = 0; n < NT; ++n) acc[n] = (f32x4){0.f, 0.f, 0.f, 0.f};
#pragma unroll
    for (int kk = 0; kk < 4; ++kk) {
        bf16x8 a = *(const bf16x8*)(arow + kk * 32);
#pragma unroll
        for (int n = 0; n < NT; ++n) {
            bf16x8 b = *(const bf16x8*)(Wf + (((kk * NT + n) * 64 + lane) << 3));
            acc[n] = __builtin_amdgcn_mfma_f32_16x16x32_bf16(a, b, acc[n], 0, 0, 0);
        }
    }
    const int NCOL = NT * 16;
    size_t crow = row0 + ((lane >> 4) << 2);
    int ccol = lane & 15;
#pragma unroll
    for (int n = 0; n < NT; ++n) {
#pragma unroll
        for (int q = 0; q < 4; ++q) {
            Hout[(crow + q) * NCOL + n * 16 + ccol] = f2bf(acc[n][q]);
        }
    }
}

// ---------- aggregation (128 ch): Out[i] = relu(sum norm*H[src] + dinv^2*H[i] + b) ----------
__global__ __launch_bounds__(256) void k_agg(const unsigned short* __restrict__ H,
                                             const int* __restrict__ row_ptr,
                                             const int* __restrict__ ssrc,
                                             const float* __restrict__ snorm,
                                             const float* __restrict__ dinv,
                                             const float* __restrict__ bias,
                                             unsigned short* __restrict__ Out, int N) {
    int lane = threadIdx.x & 63;
    int i = blockIdx.x * 4 + (threadIdx.x >> 6);
    if (i >= N) return;
    float dv = dinv[i];
    float wself = dv * dv;
    unsigned v = *(const unsigned*)(H + ((size_t)i << 7) + (lane << 1));
    float acc0 = bf2f((unsigned short)(v & 0xffff)) * wself;
    float acc1 = bf2f((unsigned short)(v >> 16)) * wself;
    int e = row_ptr[i], e1 = row_ptr[i + 1];
#pragma unroll 4
    for (; e < e1; ++e) {
        int s = ssrc[e];
        float w = snorm[e];
        unsigned hv = *(const unsigned*)(H + ((size_t)s << 7) + (lane << 1));
        acc0 += bf2f((unsigned short)(hv & 0xffff)) * w;
        acc1 += bf2f((unsigned short)(hv >> 16)) * w;
    }
    acc0 = fmaxf(acc0 + bias[lane * 2], 0.f);
    acc1 = fmaxf(acc1 + bias[lane * 2 + 1], 0.f);
    unsigned o = (unsigned)f2bf(acc0) | ((unsigned)f2bf(acc1) << 16);
    *(unsigned*)(Out + ((size_t)i << 7) + (lane << 1)) = o;
}

// ---------- final aggregation (64-padded ch, Cout real) + bias + log_softmax ----------
__global__ __launch_bounds__(256) void k_agg3(const unsigned short* __restrict__ H,
                                              const int* __restrict__ row_ptr,
                                              const int* __restrict__ ssrc,
                                              const float* __restrict__ snorm,
                                              const float* __restrict__ dinv,
                                              const float* __restrict__ b3,
                                              float* __restrict__ Out, int N, int Cout) {
    int lane = threadIdx.x & 63;
    int i = blockIdx.x * 4 + (threadIdx.x >> 6);
    if (i >= N) return;
    float dv = dinv[i];
    float acc = bf2f(H[((size_t)i << 6) + lane]) * dv * dv;
    int e = row_ptr[i], e1 = row_ptr[i + 1];
#pragma unroll 4
    for (; e < e1; ++e) {
        int s = ssrc[e];
        float w = snorm[e];
        acc += bf2f(H[((size_t)s << 6) + lane]) * w;
    }
    float z = (lane < Cout) ? acc + b3[lane] : -1e30f;
    float m = z;
    for (int off = 32; off; off >>= 1) m = fmaxf(m, __shfl_xor(m, off, 64));
    float p = (lane < Cout) ? expf(z - m) : 0.f;
    float ssum = p;
    for (int off = 32; off; off >>= 1) ssum += __shfl_xor(ssum, off, 64);
    if (lane < Cout) Out[(size_t)i * Cout + lane] = z - m - logf(ssum);
}

extern "C" void kernel_launch(void* const* d_in, const int* in_sizes, int n_in,
                              void* d_out, int out_size, void* d_ws, size_t ws_size,
                              hipStream_t stream) {
    const float* x  = (const float*)d_in[0];
    const int*   ei = (const int*)d_in[1];
    const float* W1 = (const float*)d_in[2];
    const float* b1 = (const float*)d_in[3];
    const float* W2 = (const float*)d_in[4];
    const float* b2 = (const float*)d_in[5];
    const float* W3 = (const float*)d_in[6];
    const float* b3 = (const float*)d_in[7];

    const int N = in_sizes[0] / 128;
    const int E = in_sizes[1] / 2;
    const int Cout = in_sizes[7];       // 47
    const int Npad = (N + 63) & ~63;
    const int* srcp = ei;
    const int* dstp = ei + E;

    // ---- workspace partition (256B aligned) ----
    char* p = (char*)d_ws;
    auto alloc = [&](size_t bytes) -> void* {
        void* r = (void*)p;
        p += (bytes + 255) & ~(size_t)255;
        return r;
    };
    int*   deg      = (int*)alloc((size_t)Npad * 4);
    float* dinv     = (float*)alloc((size_t)Npad * 4);
    int*   row_ptr  = (int*)alloc((size_t)(N + 1) * 4);
    int*   fill     = (int*)alloc((size_t)N * 4);
    int*   ssrc     = (int*)alloc((size_t)E * 4);
    float* snorm    = (float*)alloc((size_t)E * 4);
    unsigned short* xb  = (unsigned short*)alloc((size_t)Npad * 128 * 2);
    unsigned short* hb  = (unsigned short*)alloc((size_t)Npad * 128 * 2);
    unsigned short* ab  = (unsigned short*)alloc((size_t)Npad * 128 * 2);
    unsigned short* wf1 = (unsigned short*)alloc(128 * 128 * 2);
    unsigned short* wf2 = (unsigned short*)alloc(128 * 128 * 2);
    unsigned short* wf3 = (unsigned short*)alloc(128 * 64 * 2);

    hipMemsetAsync(deg, 0, (size_t)N * 4, stream);
    hipMemsetAsync(fill, 0, (size_t)N * 4, stream);

    // CSR build
    k_degree<<<(E + 255) / 256, 256, 0, stream>>>(dstp, E, deg);
    k_dinv<<<(N + 255) / 256, 256, 0, stream>>>(deg, dinv, N);
    k_scan<<<1, 1024, 0, stream>>>(deg, row_ptr, N);
    k_scatter<<<(E + 255) / 256, 256, 0, stream>>>(srcp, dstp, E, dinv, row_ptr, fill,
                                                   ssrc, snorm);

    // conversions
    k_cvt_x<<<(N * 128 / 4 + 255) / 256, 256, 0, stream>>>((const float4*)x, (ushort4*)xb,
                                                           N * 128 / 4);
    k_wfrag<<<(16384 + 255) / 256, 256, 0, stream>>>(W1, wf1, 128, 128);
    k_wfrag<<<(16384 + 255) / 256, 256, 0, stream>>>(W2, wf2, 128, 128);
    k_wfrag<<<(8192 + 255) / 256, 256, 0, stream>>>(W3, wf3, 64, Cout);

    const int gemmGrid = Npad / 64;
    const int aggGrid = (N + 3) / 4;

    // layer 1
    k_gemm<8><<<gemmGrid, 256, 0, stream>>>(xb, wf1, hb);
    k_agg<<<aggGrid, 256, 0, stream>>>(hb, row_ptr, ssrc, snorm, dinv, b1, ab, N);
    // layer 2
    k_gemm<8><<<gemmGrid, 256, 0, stream>>>(ab, wf2, hb);
    k_agg<<<aggGrid, 256, 0, stream>>>(hb, row_ptr, ssrc, snorm, dinv, b2, ab, N);
    // layer 3 (output padded to 64 cols) + log_softmax
    k_gemm<4><<<gemmGrid, 256, 0, stream>>>(ab, wf3, hb);
    k_agg3<<<aggGrid, 256, 0, stream>>>(hb, row_ptr, ssrc, snorm, dinv, b3,
                                        (float*)d_out, N, Cout);
}

// Round 2
// 439.209 us; speedup vs baseline: 1.3392x; 1.3392x over previous
//
#include <hip/hip_runtime.h>
#include <stdint.h>

typedef __bf16 bf16x8 __attribute__((ext_vector_type(8)));
typedef float f32x4 __attribute__((ext_vector_type(4)));

__device__ __forceinline__ float bf2f(unsigned short s) {
    union { unsigned u; float f; } x; x.u = ((unsigned)s) << 16; return x.f;
}
__device__ __forceinline__ unsigned short f2bf(float f) {
    union { float f; unsigned u; } x; x.f = f;
    unsigned r = x.u + 0x7fffu + ((x.u >> 16) & 1u);
    return (unsigned short)(r >> 16);
}

// ---------- CSR build ----------
__global__ void k_degree(const int* __restrict__ dst, int E, int* __restrict__ deg) {
    int i = blockIdx.x * blockDim.x + threadIdx.x;
    if (i < E) atomicAdd(&deg[dst[i]], 1);
}

__global__ void k_dinv(const int* __restrict__ deg, float* __restrict__ dinv, int N) {
    int i = blockIdx.x * blockDim.x + threadIdx.x;
    if (i < N) dinv[i] = rsqrtf((float)deg[i] + 1.0f);  // +1 = self loop
}

// ---------- hierarchical scan: deg[N] -> row_ptr[N+1] (exclusive) ----------
// block = 256 threads, 4 elems/thread => 1024 elems/block
__global__ __launch_bounds__(256) void k_scan_part(const int* __restrict__ deg,
                                                   int* __restrict__ part, int N) {
    __shared__ int wsum[4];
    int t = threadIdx.x;
    int lane = t & 63, wv = t >> 6;
    int base = blockIdx.x * 1024 + t * 4;
    int s = 0;
#pragma unroll
    for (int j = 0; j < 4; ++j) {
        int i = base + j;
        if (i < N) s += deg[i];
    }
    for (int off = 1; off < 64; off <<= 1) s += __shfl_xor(s, off, 64);
    if (lane == 0) wsum[wv] = s;
    __syncthreads();
    if (t == 0) part[blockIdx.x] = wsum[0] + wsum[1] + wsum[2] + wsum[3];
}

__global__ void k_scan_mid(int* __restrict__ part, int nb) {
    __shared__ int buf[256];
    int t = threadIdx.x;
    buf[t] = (t < nb) ? part[t] : 0;
    __syncthreads();
    for (int off = 1; off < 256; off <<= 1) {
        int v = buf[t];
        int u = (t >= off) ? buf[t - off] : 0;
        __syncthreads();
        buf[t] = v + u;
        __syncthreads();
    }
    if (t < nb) part[t] = (t == 0) ? 0 : buf[t - 1];
}

__global__ __launch_bounds__(256) void k_scan_final(const int* __restrict__ deg,
                                                    const int* __restrict__ part,
                                                    int* __restrict__ row_ptr, int N) {
    __shared__ int wsum[4];
    int t = threadIdx.x;
    int lane = t & 63, wv = t >> 6;
    int base = blockIdx.x * 1024 + t * 4;
    int v[4];
    int s = 0;
#pragma unroll
    for (int j = 0; j < 4; ++j) {
        int i = base + j;
        v[j] = (i < N) ? deg[i] : 0;
        s += v[j];
    }
    int inc = s;
    for (int off = 1; off < 64; off <<= 1) {
        int u = __shfl_up(inc, off, 64);
        if (lane >= off) inc += u;
    }
    if (lane == 63) wsum[wv] = inc;
    __syncthreads();
    int excl = part[blockIdx.x] + inc - s;
    for (int w = 0; w < wv; ++w) excl += wsum[w];
#pragma unroll
    for (int j = 0; j < 4; ++j) {
        int i = base + j;
        if (i < N) {
            row_ptr[i] = excl;
            excl += v[j];
            if (i == N - 1) row_ptr[N] = excl;
        }
    }
}

__global__ void k_scatter(const int* __restrict__ src, const int* __restrict__ dst, int E,
                          const float* __restrict__ dinv, const int* __restrict__ row_ptr,
                          int* __restrict__ fill, int* __restrict__ ssrc,
                          float* __restrict__ snorm) {
    int e = blockIdx.x * blockDim.x + threadIdx.x;
    if (e >= E) return;
    int s = src[e], d = dst[e];
    int pos = row_ptr[d] + atomicAdd(&fill[d], 1);
    ssrc[pos] = s;
    snorm[pos] = dinv[s] * dinv[d];
}

// ---------- conversions ----------
__global__ void k_cvt_x(const float4* __restrict__ x, ushort4* __restrict__ out, int n4) {
    int i = blockIdx.x * blockDim.x + threadIdx.x;
    if (i < n4) {
        float4 v = x[i];
        ushort4 o;
        o.x = f2bf(v.x); o.y = f2bf(v.y); o.z = f2bf(v.z); o.w = f2bf(v.w);
        out[i] = o;
    }
}

// W [K=128][realCols] f32 row-major -> fragment layout bf16:
// Wf[((kk*NT + n)*64 + lane)*8 + j] = W[kk*32 + (lane>>4)*8 + j][n*16 + (lane&15)]
__global__ void k_wfrag(const float* __restrict__ W, unsigned short* __restrict__ Wf,
                        int Ncol, int realCols) {
    int NT = Ncol >> 4;
    int total = 4 * NT * 64 * 8;
    int idx = blockIdx.x * blockDim.x + threadIdx.x;
    if (idx >= total) return;
    int j = idx & 7;
    int l = (idx >> 3) & 63;
    int t = idx >> 9;          // kk*NT + n
    int n = t % NT;
    int kk = t / NT;
    int k = kk * 32 + ((l >> 4) << 3) + j;
    int c = (n << 4) + (l & 15);
    float v = (c < realCols) ? W[k * realCols + c] : 0.0f;
    Wf[idx] = f2bf(v);
}

// ---------- GEMM: H[Npad][NT*16] = A[Npad][128] @ W (frag layout) ----------
template<int NT>
__global__ __launch_bounds__(256) void k_gemm(const unsigned short* __restrict__ A,
                                              const unsigned short* __restrict__ Wf,
                                              unsigned short* __restrict__ Hout) {
    int lane = threadIdx.x & 63;
    int wv = threadIdx.x >> 6;
    int rb = blockIdx.x * 4 + wv;
    size_t row0 = (size_t)rb * 16;
    const unsigned short* arow = A + (row0 + (lane & 15)) * 128 + ((lane >> 4) << 3);
    f32x4 acc[NT];
#pragma unroll
    for (int n = 0; n < NT; ++n) acc[n] = (f32x4){0.f, 0.f, 0.f, 0.f};
#pragma unroll
    for (int kk = 0; kk < 4; ++kk) {
        bf16x8 a = *(const bf16x8*)(arow + kk * 32);
#pragma unroll
        for (int n = 0; n < NT; ++n) {
            bf16x8 b = *(const bf16x8*)(Wf + (((kk * NT + n) * 64 + lane) << 3));
            acc[n] = __builtin_amdgcn_mfma_f32_16x16x32_bf16(a, b, acc[n], 0, 0, 0);
        }
    }
    const int NCOL = NT * 16;
    size_t crow = row0 + ((lane >> 4) << 2);
    int ccol = lane & 15;
#pragma unroll
    for (int n = 0; n < NT; ++n) {
#pragma unroll
        for (int q = 0; q < 4; ++q) {
            Hout[(crow + q) * NCOL + n * 16 + ccol] = f2bf(acc[n][q]);
        }
    }
}

// ---------- aggregation (128 ch): Out[i] = relu(sum norm*H[src] + dinv^2*H[i] + b) ----------
__global__ __launch_bounds__(256) void k_agg(const unsigned short* __restrict__ H,
                                             const int* __restrict__ row_ptr,
                                             const int* __restrict__ ssrc,
                                             const float* __restrict__ snorm,
                                             const float* __restrict__ dinv,
                                             const float* __restrict__ bias,
                                             unsigned short* __restrict__ Out, int N) {
    int lane = threadIdx.x & 63;
    int i = blockIdx.x * 4 + (threadIdx.x >> 6);
    if (i >= N) return;
    float dv = dinv[i];
    float wself = dv * dv;
    unsigned v = *(const unsigned*)(H + ((size_t)i << 7) + (lane << 1));
    float acc0 = bf2f((unsigned short)(v & 0xffff)) * wself;
    float acc1 = bf2f((unsigned short)(v >> 16)) * wself;
    int e = row_ptr[i], e1 = row_ptr[i + 1];
#pragma unroll 4
    for (; e < e1; ++e) {
        int s = ssrc[e];
        float w = snorm[e];
        unsigned hv = *(const unsigned*)(H + ((size_t)s << 7) + (lane << 1));
        acc0 += bf2f((unsigned short)(hv & 0xffff)) * w;
        acc1 += bf2f((unsigned short)(hv >> 16)) * w;
    }
    acc0 = fmaxf(acc0 + bias[lane * 2], 0.f);
    acc1 = fmaxf(acc1 + bias[lane * 2 + 1], 0.f);
    unsigned o = (unsigned)f2bf(acc0) | ((unsigned)f2bf(acc1) << 16);
    *(unsigned*)(Out + ((size_t)i << 7) + (lane << 1)) = o;
}

// ---------- final aggregation (64-padded ch, Cout real) + bias + log_softmax ----------
__global__ __launch_bounds__(256) void k_agg3(const unsigned short* __restrict__ H,
                                              const int* __restrict__ row_ptr,
                                              const int* __restrict__ ssrc,
                                              const float* __restrict__ snorm,
                                              const float* __restrict__ dinv,
                                              const float* __restrict__ b3,
                                              float* __restrict__ Out, int N, int Cout) {
    int lane = threadIdx.x & 63;
    int i = blockIdx.x * 4 + (threadIdx.x >> 6);
    if (i >= N) return;
    float dv = dinv[i];
    float acc = bf2f(H[((size_t)i << 6) + lane]) * dv * dv;
    int e = row_ptr[i], e1 = row_ptr[i + 1];
#pragma unroll 4
    for (; e < e1; ++e) {
        int s = ssrc[e];
        float w = snorm[e];
        acc += bf2f(H[((size_t)s << 6) + lane]) * w;
    }
    float z = (lane < Cout) ? acc + b3[lane] : -1e30f;
    float m = z;
    for (int off = 32; off; off >>= 1) m = fmaxf(m, __shfl_xor(m, off, 64));
    float p = (lane < Cout) ? expf(z - m) : 0.f;
    float ssum = p;
    for (int off = 32; off; off >>= 1) ssum += __shfl_xor(ssum, off, 64);
    if (lane < Cout) Out[(size_t)i * Cout + lane] = z - m - logf(ssum);
}

extern "C" void kernel_launch(void* const* d_in, const int* in_sizes, int n_in,
                              void* d_out, int out_size, void* d_ws, size_t ws_size,
                              hipStream_t stream) {
    const float* x  = (const float*)d_in[0];
    const int*   ei = (const int*)d_in[1];
    const float* W1 = (const float*)d_in[2];
    const float* b1 = (const float*)d_in[3];
    const float* W2 = (const float*)d_in[4];
    const float* b2 = (const float*)d_in[5];
    const float* W3 = (const float*)d_in[6];
    const float* b3 = (const float*)d_in[7];

    const int N = in_sizes[0] / 128;
    const int E = in_sizes[1] / 2;
    const int Cout = in_sizes[7];       // 47
    const int Npad = (N + 63) & ~63;
    const int* srcp = ei;
    const int* dstp = ei + E;

    // ---- workspace partition (256B aligned) ----
    char* p = (char*)d_ws;
    auto alloc = [&](size_t bytes) -> void* {
        void* r = (void*)p;
        p += (bytes + 255) & ~(size_t)255;
        return r;
    };
    int*   deg      = (int*)alloc((size_t)Npad * 4);
    float* dinv     = (float*)alloc((size_t)Npad * 4);
    int*   row_ptr  = (int*)alloc((size_t)(N + 1) * 4);
    int*   fill     = (int*)alloc((size_t)N * 4);
    int*   part     = (int*)alloc(1024 * 4);
    int*   ssrc     = (int*)alloc((size_t)E * 4);
    float* snorm    = (float*)alloc((size_t)E * 4);
    unsigned short* xb  = (unsigned short*)alloc((size_t)Npad * 128 * 2);
    unsigned short* hb  = (unsigned short*)alloc((size_t)Npad * 128 * 2);
    unsigned short* ab  = (unsigned short*)alloc((size_t)Npad * 128 * 2);
    unsigned short* wf1 = (unsigned short*)alloc(128 * 128 * 2);
    unsigned short* wf2 = (unsigned short*)alloc(128 * 128 * 2);
    unsigned short* wf3 = (unsigned short*)alloc(128 * 64 * 2);

    hipMemsetAsync(deg, 0, (size_t)N * 4, stream);
    hipMemsetAsync(fill, 0, (size_t)N * 4, stream);

    // CSR build
    const int nb = (N + 1023) / 1024;   // 98 blocks for N=100k (must be <= 256)
    k_degree<<<(E + 255) / 256, 256, 0, stream>>>(dstp, E, deg);
    k_dinv<<<(N + 255) / 256, 256, 0, stream>>>(deg, dinv, N);
    k_scan_part<<<nb, 256, 0, stream>>>(deg, part, N);
    k_scan_mid<<<1, 256, 0, stream>>>(part, nb);
    k_scan_final<<<nb, 256, 0, stream>>>(deg, part, row_ptr, N);
    k_scatter<<<(E + 255) / 256, 256, 0, stream>>>(srcp, dstp, E, dinv, row_ptr, fill,
                                                   ssrc, snorm);

    // conversions
    k_cvt_x<<<(N * 128 / 4 + 255) / 256, 256, 0, stream>>>((const float4*)x, (ushort4*)xb,
                                                           N * 128 / 4);
    k_wfrag<<<(16384 + 255) / 256, 256, 0, stream>>>(W1, wf1, 128, 128);
    k_wfrag<<<(16384 + 255) / 256, 256, 0, stream>>>(W2, wf2, 128, 128);
    k_wfrag<<<(8192 + 255) / 256, 256, 0, stream>>>(W3, wf3, 64, Cout);

    const int gemmGrid = Npad / 64;
    const int aggGrid = (N + 3) / 4;

    // layer 1
    k_gemm<8><<<gemmGrid, 256, 0, stream>>>(xb, wf1, hb);
    k_agg<<<aggGrid, 256, 0, stream>>>(hb, row_ptr, ssrc, snorm, dinv, b1, ab, N);
    // layer 2
    k_gemm<8><<<gemmGrid, 256, 0, stream>>>(ab, wf2, hb);
    k_agg<<<aggGrid, 256, 0, stream>>>(hb, row_ptr, ssrc, snorm, dinv, b2, ab, N);
    // layer 3 (output padded to 64 cols) + log_softmax
    k_gemm<4><<<gemmGrid, 256, 0, stream>>>(ab, wf3, hb);
    k_agg3<<<aggGrid, 256, 0, stream>>>(hb, row_ptr, ssrc, snorm, dinv, b3,
                                        (float*)d_out, N, Cout);
}